// Round 7
// baseline (57.815 us; speedup 1.0000x reference)
//
#include <hip/hip_runtime.h>
#include <hip/hip_bf16.h>
#include <stdint.h>

// Problem constants (B,T,C,E) = (4,2048,1024,8)
#define NB 4
#define NT 2048
#define NC 1024
#define NE 8
#define NTOK (NB * NT)              // 8192 tokens
#define MAXT (NTOK / 128 + NE - 1)  // 71 worst-case M-tiles across experts
#define CSTRIDE 32                  // counter padding: 32 ints = 128 B / expert

typedef __attribute__((ext_vector_type(4))) float floatx4;
typedef __attribute__((ext_vector_type(8))) __bf16 bf16x8;
typedef __attribute__((ext_vector_type(4))) __bf16 bf16x4;
typedef unsigned short ushort_t;

#define AS1 __attribute__((address_space(1)))
#define AS3 __attribute__((address_space(3)))

__device__ __forceinline__ ushort_t f2bf(float f) {
    uint32_t u = __builtin_bit_cast(uint32_t, f);
    u += 0x7FFFu + ((u >> 16) & 1u);   // round-to-nearest-even
    return (ushort_t)(u >> 16);
}

// Zero the padded counters with a kernel: a graph-captured hipMemsetAsync
// (fillBufferAligned) has a ~40 us dispatch floor REGARDLESS of size
// (measured rounds 5/6: 1 KB fill = 40.5 us, 33 MB fill = 40.1 us).
__global__ void zero_counts_k(int* __restrict__ counts) {
    if (threadIdx.x < NE) counts[threadIdx.x * CSTRIDE] = 0;
}

// One wave per token. Stream-through phases: (A) We->bf16 convert slice with
// immediate stores, (B) x row load, (C) fp32 routing math, (D) routed ->
// {bf16 x row store + bucket atomic} / unrouted -> {zero output row}.
__global__ __launch_bounds__(256, 4) void router_k(
    const float* __restrict__ x, const float* __restrict__ Wr,
    const float* __restrict__ br, float* __restrict__ out,
    int* __restrict__ counts, int* __restrict__ buckets,
    ushort_t* __restrict__ xbf /* null on fallback */,
    const float* __restrict__ We, ushort_t* __restrict__ webf /* null on fallback */)
{
    const int wave = threadIdx.x >> 6;
    const int lane = threadIdx.x & 63;
    const int tok  = blockIdx.x * 4 + wave;

    // --- Phase A: fused We convert, stream-through (2 x 32B/thread) ---
    if (webf) {
        const size_t cbase = ((size_t)(blockIdx.x * 256 + threadIdx.x)) * 8;
        {
            float4 a = *(const float4*)(We + cbase);
            float4 b = *(const float4*)(We + cbase + 4);
            union { bf16x8 v; ushort_t s[8]; } p;
            p.s[0] = f2bf(a.x); p.s[1] = f2bf(a.y); p.s[2] = f2bf(a.z); p.s[3] = f2bf(a.w);
            p.s[4] = f2bf(b.x); p.s[5] = f2bf(b.y); p.s[6] = f2bf(b.z); p.s[7] = f2bf(b.w);
            *(bf16x8*)(webf + cbase) = p.v;
        }
        {
            float4 a = *(const float4*)(We + cbase + 4194304);
            float4 b = *(const float4*)(We + cbase + 4194304 + 4);
            union { bf16x8 v; ushort_t s[8]; } p;
            p.s[0] = f2bf(a.x); p.s[1] = f2bf(a.y); p.s[2] = f2bf(a.z); p.s[3] = f2bf(a.w);
            p.s[4] = f2bf(b.x); p.s[5] = f2bf(b.y); p.s[6] = f2bf(b.z); p.s[7] = f2bf(b.w);
            *(bf16x8*)(webf + cbase + 4194304) = p.v;
        }
    }

    // --- Phase B: x row load ---
    const float4* xr = (const float4*)(x + (size_t)tok * NC);
    float4 xv[4];
#pragma unroll
    for (int j = 0; j < 4; ++j) xv[j] = xr[lane + 64 * j];

    // --- Phase C: fp32 routing ---
    float acc[NE];
#pragma unroll
    for (int e = 0; e < NE; ++e) {
        const float4* wr = (const float4*)(Wr + e * NC);
        float a = 0.f;
#pragma unroll
        for (int j = 0; j < 4; ++j) {
            float4 w = wr[lane + 64 * j];
            a += xv[j].x * w.x; a += xv[j].y * w.y;
            a += xv[j].z * w.z; a += xv[j].w * w.w;
        }
        acc[e] = a;
    }
#pragma unroll
    for (int off = 32; off >= 1; off >>= 1)
#pragma unroll
        for (int e = 0; e < NE; ++e) acc[e] += __shfl_xor(acc[e], off);

#pragma unroll
    for (int e = 0; e < NE; ++e) acc[e] += br[e];

    float lmax = acc[0]; int emax = 0;
#pragma unroll
    for (int e = 1; e < NE; ++e) if (acc[e] > lmax) { lmax = acc[e]; emax = e; }
    float S = 0.f;
#pragma unroll
    for (int e = 0; e < NE; ++e) S += expf(acc[e] - lmax);

    // --- Phase D: wave-uniform routed/unrouted paths ---
    const bool routed = (S < 2.0f);   // gate_max = 1/S > 0.5
    if (routed) {
        if (xbf) {  // bf16 x row needed only for routed tokens
            union { bf16x4 v; ushort_t s[4]; } p;
#pragma unroll
            for (int j = 0; j < 4; ++j) {
                p.s[0] = f2bf(xv[j].x); p.s[1] = f2bf(xv[j].y);
                p.s[2] = f2bf(xv[j].z); p.s[3] = f2bf(xv[j].w);
                *(bf16x4*)(xbf + (size_t)tok * NC + (lane + 64 * j) * 4) = p.v;
            }
        }
        if (lane == 0) {
            int pos = atomicAdd(&counts[emax * CSTRIDE], 1);
            buckets[emax * NTOK + pos] = tok;
        }
    } else {
        float4 z = make_float4(0.f, 0.f, 0.f, 0.f);
        float4* orow = (float4*)(out + (size_t)tok * NC);
#pragma unroll
        for (int j = 0; j < 4; ++j) orow[lane + 64 * j] = z;
    }
}

__device__ __forceinline__ void gload_lds16(const void* g, void* l) {
    __builtin_amdgcn_global_load_lds((const AS1 unsigned int*)g,
                                     (AS3 unsigned int*)l, 16, 0, 0);
}

// ---------- fast path: bf16 grouped GEMM, compacted grid + XOR swizzle ----------
__global__ __launch_bounds__(256) void moe_gemm_bf16_k(
    const ushort_t* __restrict__ xbf, const ushort_t* __restrict__ webf,
    const float* __restrict__ be, float* __restrict__ out,
    const int* __restrict__ counts, const int* __restrict__ buckets)
{
    int cw[NE];
#pragma unroll
    for (int i = 0; i < NE; ++i) cw[i] = counts[i * CSTRIDE];
    const int t = blockIdx.x;
    int base = 0, e = -1, m0 = 0;
#pragma unroll
    for (int i = 0; i < NE; ++i) {
        const int te = (cw[i] + 127) >> 7;
        if (e < 0 && t < base + te) { e = i; m0 = (t - base) << 7; }
        base += te;
    }
    if (e < 0) return;
    const int cnt = cw[e];
    const int n0  = blockIdx.y * 128;

    __shared__ ushort_t As[128 * 64];   // 16 KB, linear (gload_lds dest)
    __shared__ ushort_t Bs[128 * 64];   // 16 KB

    const int tid   = threadIdx.x;
    const int wave  = tid >> 6, lane = tid & 63;
    const int chunk = tid & 7;          // 16B chunk within a 64-elem K-slice
    const int rbase = tid >> 3;         // 0..31

    const ushort_t* asrc[4];
    const ushort_t* bsrc[4];
#pragma unroll
    for (int i = 0; i < 4; ++i) {
        const int row = i * 32 + rbase;            // 0..127
        const int sc  = chunk ^ (row & 7);         // pre-swizzled source chunk
        int mi = m0 + row; if (mi >= cnt) mi = cnt - 1;
        const int tok = buckets[e * NTOK + mi];
        asrc[i] = xbf + (size_t)tok * NC + sc * 8;
        bsrc[i] = webf + ((size_t)(e * 1024 + n0 + row)) * NC + sc * 8;
    }

    const int wm = (wave >> 1) * 64, wn = (wave & 1) * 64;
    const int fr = lane & 15, hi = lane >> 4;

    floatx4 acc[4][4];
#pragma unroll
    for (int m = 0; m < 4; ++m)
#pragma unroll
        for (int n = 0; n < 4; ++n) acc[m][n] = (floatx4)(0.0f);

    for (int k0 = 0; k0 < NC; k0 += 64) {
#pragma unroll
        for (int i = 0; i < 4; ++i)
            gload_lds16(asrc[i] + k0, &As[(i * 256 + tid) * 8]);
#pragma unroll
        for (int i = 0; i < 4; ++i)
            gload_lds16(bsrc[i] + k0, &Bs[(i * 256 + tid) * 8]);
        __syncthreads();   // staging complete
#pragma unroll
        for (int ks = 0; ks < 2; ++ks) {
            bf16x8 af[4], bfv[4];
#pragma unroll
            for (int m = 0; m < 4; ++m) {
                const int row = wm + m * 16 + fr;
                const int cg  = (ks * 4 + hi) ^ (row & 7);   // swizzled read chunk
                af[m] = *(const bf16x8*)((const char*)As + row * 128 + cg * 16);
            }
#pragma unroll
            for (int n = 0; n < 4; ++n) {
                const int row = wn + n * 16 + fr;
                const int cg  = (ks * 4 + hi) ^ (row & 7);
                bfv[n] = *(const bf16x8*)((const char*)Bs + row * 128 + cg * 16);
            }
#pragma unroll
            for (int m = 0; m < 4; ++m)
#pragma unroll
                for (int n = 0; n < 4; ++n)
                    acc[m][n] = __builtin_amdgcn_mfma_f32_16x16x32_bf16(
                        af[m], bfv[n], acc[m][n], 0, 0, 0);
        }
        __syncthreads();   // safe to overwrite LDS
    }

    // Epilogue: D layout col=lane&15, row=(lane>>4)*4+reg (m89-verified)
    const int r4 = (lane >> 4) * 4;
    float bev[4];
#pragma unroll
    for (int n = 0; n < 4; ++n) bev[n] = be[e * NC + n0 + wn + n * 16 + fr];
#pragma unroll
    for (int m = 0; m < 4; ++m) {
#pragma unroll
        for (int j = 0; j < 4; ++j) {
            const int trow = m0 + wm + m * 16 + r4 + j;
            if (trow < cnt) {
                const int tok = buckets[e * NTOK + trow];
                float* orow = out + (size_t)tok * NC + n0 + wn + fr;
#pragma unroll
                for (int n = 0; n < 4; ++n) orow[n * 16] = acc[m][n][j] + bev[n];
            }
        }
    }
}

// ---------- fallback path (fp32 staging, small ws) ----------
#define BM 64
#define BN 64
#define BK 32
#define LPAD 40
__global__ __launch_bounds__(256) void moe_gemm_k(
    const float* __restrict__ x, const float* __restrict__ We,
    const float* __restrict__ be, float* __restrict__ out,
    const int* __restrict__ counts, const int* __restrict__ buckets)
{
    const int e   = blockIdx.z;
    const int cnt = counts[e * CSTRIDE];
    const int m0  = blockIdx.x * BM;
    if (m0 >= cnt) return;
    const int n0  = blockIdx.y * BN;

    __shared__ ushort_t As[BM * LPAD];
    __shared__ ushort_t Bs[BM * LPAD];

    const int tid  = threadIdx.x;
    const int srow = tid >> 2;
    const int scg  = (tid & 3) * 8;

    const int mrow = m0 + srow;
    const int tokA = (mrow < cnt) ? buckets[e * NTOK + mrow] : -1;
    const float* xrow = x + (size_t)(tokA < 0 ? 0 : tokA) * NC;
    const float* wrow = We + ((size_t)e * NC + (n0 + srow)) * NC;

    const int wave = tid >> 6, lane = tid & 63;
    const int wm = (wave >> 1) * 32, wn = (wave & 1) * 32;
    const int fr = lane & 15;
    const int fk = (lane >> 4) * 8;

    floatx4 acc[2][2];
#pragma unroll
    for (int m = 0; m < 2; ++m)
#pragma unroll
        for (int n = 0; n < 2; ++n) acc[m][n] = (floatx4)(0.0f);

    for (int k0 = 0; k0 < NC; k0 += BK) {
        float4 a0 = make_float4(0.f,0.f,0.f,0.f), a1 = a0;
        if (tokA >= 0) {
            a0 = *(const float4*)(xrow + k0 + scg);
            a1 = *(const float4*)(xrow + k0 + scg + 4);
        }
        float4 b0 = *(const float4*)(wrow + k0 + scg);
        float4 b1 = *(const float4*)(wrow + k0 + scg + 4);

        __syncthreads();
        union { bf16x8 v; ushort_t s[8]; } pa, pb;
        pa.s[0] = f2bf(a0.x); pa.s[1] = f2bf(a0.y); pa.s[2] = f2bf(a0.z); pa.s[3] = f2bf(a0.w);
        pa.s[4] = f2bf(a1.x); pa.s[5] = f2bf(a1.y); pa.s[6] = f2bf(a1.z); pa.s[7] = f2bf(a1.w);
        pb.s[0] = f2bf(b0.x); pb.s[1] = f2bf(b0.y); pb.s[2] = f2bf(b0.z); pb.s[3] = f2bf(b0.w);
        pb.s[4] = f2bf(b1.x); pb.s[5] = f2bf(b1.y); pb.s[6] = f2bf(b1.z); pb.s[7] = f2bf(b1.w);
        *(bf16x8*)&As[srow * LPAD + scg] = pa.v;
        *(bf16x8*)&Bs[srow * LPAD + scg] = pb.v;
        __syncthreads();

        bf16x8 af[2], bfr[2];
#pragma unroll
        for (int m = 0; m < 2; ++m)
            af[m] = *(const bf16x8*)&As[(wm + m * 16 + fr) * LPAD + fk];
#pragma unroll
        for (int n = 0; n < 2; ++n)
            bfr[n] = *(const bf16x8*)&Bs[(wn + n * 16 + fr) * LPAD + fk];
#pragma unroll
        for (int m = 0; m < 2; ++m)
#pragma unroll
            for (int n = 0; n < 2; ++n)
                acc[m][n] = __builtin_amdgcn_mfma_f32_16x16x32_bf16(af[m], bfr[n], acc[m][n], 0, 0, 0);
    }

    const int r4 = (lane >> 4) * 4;
#pragma unroll
    for (int m = 0; m < 2; ++m) {
        const int trowb = m0 + wm + m * 16 + r4;
#pragma unroll
        for (int j = 0; j < 4; ++j) {
            const int trow = trowb + j;
            if (trow < cnt) {
                const int tok = buckets[e * NTOK + trow];
#pragma unroll
                for (int n = 0; n < 2; ++n) {
                    const int d = n0 + wn + n * 16 + fr;
                    out[(size_t)tok * NC + d] = acc[m][n][j] + be[e * NC + d];
                }
            }
        }
    }
}

extern "C" void kernel_launch(void* const* d_in, const int* in_sizes, int n_in,
                              void* d_out, int out_size, void* d_ws, size_t ws_size,
                              hipStream_t stream)
{
    const float* x  = (const float*)d_in[0];
    const float* Wr = (const float*)d_in[1];
    const float* br = (const float*)d_in[2];
    const float* We = (const float*)d_in[3];
    const float* be = (const float*)d_in[4];
    float* out = (float*)d_out;

    // ws layout (bytes):
    //   [0, 1024)              padded counts (8 x 128B)
    //   [1024, 1024+262144)    buckets (8 x 8192 ints)      -> ends 263168
    //   [263168, +16777216)    x bf16                        -> ends 17040384
    //   [17040384, +16777216)  We bf16                       -> ends 33817600
    int* counts  = (int*)d_ws;
    int* buckets = (int*)((char*)d_ws + 1024);
    const size_t XBF_OFF = 263168;
    const size_t WBF_OFF = 17040384;
    const size_t WS_NEED = 33817600;
    const bool fast = (ws_size >= WS_NEED);

    ushort_t* xbf  = fast ? (ushort_t*)((char*)d_ws + XBF_OFF) : nullptr;
    ushort_t* webf = fast ? (ushort_t*)((char*)d_ws + WBF_OFF) : nullptr;

    hipLaunchKernelGGL(zero_counts_k, dim3(1), dim3(64), 0, stream, counts);
    hipLaunchKernelGGL(router_k, dim3(NTOK / 4), dim3(256), 0, stream,
                       x, Wr, br, out, counts, buckets, xbf, We, webf);
    if (fast) {
        hipLaunchKernelGGL(moe_gemm_bf16_k, dim3(MAXT, NC / 128, 1), dim3(256),
                           0, stream, xbf, webf, be, out, counts, buckets);
    } else {
        hipLaunchKernelGGL(moe_gemm_k, dim3(NTOK / BM, NC / BN, NE), dim3(256),
                           0, stream, x, We, be, out, counts, buckets);
    }
}